// Round 1
// baseline (130.528 us; speedup 1.0000x reference)
//
#include <hip/hip_runtime.h>

// LIF spiking scan: x[B=8, S=2048, H=4096] f32 -> spikes[B,S,H] f32.
// Sequential over S per (b,h); parallel over B*H = 32768 threads = 512 waves.
// Thread = one (b,h) sequence; lane dim = h -> 256B coalesced wave accesses.
// Bit-exactness vs numpy: leak uses UNFUSED __fmul_rn + __fadd_rn (FMA
// contraction flips borderline threshold comparisons -> chaotic spike flips).

#define S_LEN 2048
#define H_DIM 4096
#define B_DIM 8
#define UNR 32  // prefetch depth per buffer; 2 buffers -> up to 64 loads in flight

__global__ __launch_bounds__(64, 1) void lif_kernel(
    const float* __restrict__ x,
    const float* __restrict__ thr_p,
    const float* __restrict__ decay_p,
    float* __restrict__ out)
{
    const int tid = blockIdx.x * 64 + threadIdx.x;   // 0 .. 32767
    const int b = tid >> 12;                         // tid / H_DIM
    const int h = tid & (H_DIM - 1);

    const float thr   = thr_p[0];
    const float decay = decay_p[0];

    const size_t base = (size_t)b * S_LEN * H_DIM + (size_t)h;
    const float* xp = x + base;
    float*       op = out + base;

    float mem = 0.0f;
    float ref = 0.0f;

    float buf0[UNR], buf1[UNR];

    // Prologue: fill buf0 with timesteps [0, UNR).
#pragma unroll
    for (int u = 0; u < UNR; ++u)
        buf0[u] = xp[(size_t)u * H_DIM];

    for (int s = 0; s < S_LEN; s += 2 * UNR) {
        // Prefetch buf1 = timesteps [s+UNR, s+2*UNR) while we consume buf0.
#pragma unroll
        for (int u = 0; u < UNR; ++u)
            buf1[u] = xp[(size_t)(s + UNR + u) * H_DIM];

        // Consume buf0.
#pragma unroll
        for (int u = 0; u < UNR; ++u) {
            // mem = decay*mem + x  -- two roundings, matching numpy exactly.
            const float memn = __fadd_rn(__fmul_rn(decay, mem), buf0[u]);
            ref = fmaxf(__fadd_rn(ref, -1.0f), 0.0f);        // clamp(ref-1, 0)
            const bool  spk_b = (ref == 0.0f) & (memn > thr);
            const float spk   = spk_b ? 1.0f : 0.0f;
            mem = spk_b ? 0.0f : memn;                       // == mem*(1-spk) exactly
            ref = __fadd_rn(ref, spk_b ? 5.0f : 0.0f);       // ref + spk*5 (exact)
            op[(size_t)(s + u) * H_DIM] = spk;
        }

        // Prefetch buf0 = timesteps [s+2*UNR, s+3*UNR) for next iteration.
        if (s + 2 * UNR < S_LEN) {
#pragma unroll
            for (int u = 0; u < UNR; ++u)
                buf0[u] = xp[(size_t)(s + 2 * UNR + u) * H_DIM];
        }

        // Consume buf1.
#pragma unroll
        for (int u = 0; u < UNR; ++u) {
            const float memn = __fadd_rn(__fmul_rn(decay, mem), buf1[u]);
            ref = fmaxf(__fadd_rn(ref, -1.0f), 0.0f);
            const bool  spk_b = (ref == 0.0f) & (memn > thr);
            const float spk   = spk_b ? 1.0f : 0.0f;
            mem = spk_b ? 0.0f : memn;
            ref = __fadd_rn(ref, spk_b ? 5.0f : 0.0f);
            op[(size_t)(s + UNR + u) * H_DIM] = spk;
        }
    }
}

extern "C" void kernel_launch(void* const* d_in, const int* in_sizes, int n_in,
                              void* d_out, int out_size, void* d_ws, size_t ws_size,
                              hipStream_t stream) {
    const float* x     = (const float*)d_in[0];
    const float* thr   = (const float*)d_in[1];
    const float* decay = (const float*)d_in[2];
    float*       out   = (float*)d_out;

    // B*H = 32768 threads; 512 blocks x 64 -> 2 blocks per CU on 256 CUs.
    lif_kernel<<<dim3(512), dim3(64), 0, stream>>>(x, thr, decay, out);
}

// Round 2
// 121.329 us; speedup vs baseline: 1.0758x; 1.0758x over previous
//
#include <hip/hip_runtime.h>

// LIF spiking scan: x[B=8, S=2048, H=4096] f32 -> spikes[B,S,H] f32.
// Sequential over S per (b,h); parallel over B*H = 32768 threads = 512 waves
// = 2 waves/CU (structural). BW must come from MLP: 64-deep double-buffered
// register prefetch -> up to 16 KB in flight per wave, 32 KB/CU.
// Bit-exactness vs numpy: leak uses UNFUSED __fmul_rn + __fadd_rn (FMA
// contraction flips borderline threshold comparisons -> chaotic spike flips).
// Streams have zero reuse -> nontemporal load/store to avoid L2/L3 thrash.

#define S_LEN 2048
#define H_DIM 4096
#define UNR 64  // prefetch depth per buffer; 2 buffers

__global__ __launch_bounds__(64, 1) void lif_kernel(
    const float* __restrict__ x,
    const float* __restrict__ thr_p,
    const float* __restrict__ decay_p,
    float* __restrict__ out)
{
    const int tid = blockIdx.x * 64 + threadIdx.x;   // 0 .. 32767
    const int b = tid >> 12;                         // tid / H_DIM
    const int h = tid & (H_DIM - 1);

    const float thr   = thr_p[0];
    const float decay = decay_p[0];

    const size_t base = (size_t)b * S_LEN * H_DIM + (size_t)h;
    const float* xp = x + base;
    float*       op = out + base;

    float mem = 0.0f;
    float ref = 0.0f;

    float buf0[UNR], buf1[UNR];

    // Prologue: fill buf0 with timesteps [0, UNR).
#pragma unroll
    for (int u = 0; u < UNR; ++u)
        buf0[u] = __builtin_nontemporal_load(&xp[(size_t)u * H_DIM]);

    for (int s = 0; s < S_LEN; s += 2 * UNR) {
        // Prefetch buf1 = timesteps [s+UNR, s+2*UNR) while we consume buf0.
#pragma unroll
        for (int u = 0; u < UNR; ++u)
            buf1[u] = __builtin_nontemporal_load(&xp[(size_t)(s + UNR + u) * H_DIM]);

        // Consume buf0.
#pragma unroll
        for (int u = 0; u < UNR; ++u) {
            // mem = decay*mem + x  -- two roundings, matching numpy exactly.
            const float memn = __fadd_rn(__fmul_rn(decay, mem), buf0[u]);
            ref = fmaxf(__fadd_rn(ref, -1.0f), 0.0f);        // clamp(ref-1, 0)
            const bool  spk_b = (ref == 0.0f) & (memn > thr);
            const float spk   = spk_b ? 1.0f : 0.0f;
            mem = spk_b ? 0.0f : memn;                       // == mem*(1-spk) exactly
            ref = __fadd_rn(ref, spk_b ? 5.0f : 0.0f);       // ref + spk*5 (exact)
            __builtin_nontemporal_store(spk, &op[(size_t)(s + u) * H_DIM]);
        }

        // Prefetch buf0 = timesteps [s+2*UNR, s+3*UNR) for next iteration.
        if (s + 2 * UNR < S_LEN) {
#pragma unroll
            for (int u = 0; u < UNR; ++u)
                buf0[u] = __builtin_nontemporal_load(&xp[(size_t)(s + 2 * UNR + u) * H_DIM]);
        }

        // Consume buf1.
#pragma unroll
        for (int u = 0; u < UNR; ++u) {
            const float memn = __fadd_rn(__fmul_rn(decay, mem), buf1[u]);
            ref = fmaxf(__fadd_rn(ref, -1.0f), 0.0f);
            const bool  spk_b = (ref == 0.0f) & (memn > thr);
            const float spk   = spk_b ? 1.0f : 0.0f;
            mem = spk_b ? 0.0f : memn;
            ref = __fadd_rn(ref, spk_b ? 5.0f : 0.0f);
            __builtin_nontemporal_store(spk, &op[(size_t)(s + UNR + u) * H_DIM]);
        }
    }
}

extern "C" void kernel_launch(void* const* d_in, const int* in_sizes, int n_in,
                              void* d_out, int out_size, void* d_ws, size_t ws_size,
                              hipStream_t stream) {
    const float* x     = (const float*)d_in[0];
    const float* thr   = (const float*)d_in[1];
    const float* decay = (const float*)d_in[2];
    float*       out   = (float*)d_out;

    // B*H = 32768 threads; 512 blocks x 64 -> 2 single-wave blocks per CU.
    lif_kernel<<<dim3(512), dim3(64), 0, stream>>>(x, thr, decay, out);
}

// Round 4
// 107.163 us; speedup vs baseline: 1.2180x; 1.1322x over previous
//
#include <hip/hip_runtime.h>
#include <stdint.h>

// LIF spiking scan: x[B=8, S=2048, H=4096] f32 -> spikes[B,S,H] f32.
// 512 waves (2/CU, structural). R2 insight: vmcnt caps outstanding VMEM ops
// at 63/wave, so MLP must come from BYTES PER OP, not op count.
// -> 64-timestep LDS tiles: loads = 16x global_load_lds width-16 (1KB/op),
//    stores = ds_write to LDS out-tile, flushed as 16x dwordx4 (1KB/op).
// Counted vmcnt waits (never drain-to-0) keep ~48KB in flight per wave.
// Bit-exact vs numpy: unfused __fmul_rn+__fadd_rn leak (FMA contraction
// flips borderline threshold comparisons -> chaotic spike flips).

#define S_LEN 2048
#define H_DIM 4096
#define TS 64              // timesteps per tile
#define NT (S_LEN / TS)    // 32 tiles

typedef __attribute__((address_space(3))) uint32_t lds_u32;
typedef __attribute__((address_space(1))) const uint32_t gbl_u32;
typedef float f32x4 __attribute__((ext_vector_type(4)));  // native vec for nontemporal builtins

__global__ __launch_bounds__(64, 1) void lif_kernel(
    const float* __restrict__ x,
    const float* __restrict__ thr_p,
    const float* __restrict__ decay_p,
    float* __restrict__ out)
{
    __shared__ __attribute__((aligned(16))) float xbuf[2][TS][64];  // 32 KB
    __shared__ __attribute__((aligned(16))) float obuf[2][TS][64];  // 32 KB

    const int lane = threadIdx.x;            // 0..63
    const int b    = blockIdx.x >> 6;        // 0..7
    const int h0   = (blockIdx.x & 63) * 64; // h-tile origin

    const float thr   = thr_p[0];
    const float decay = decay_p[0];

    const size_t seq_base = (size_t)b * S_LEN * H_DIM;
    const int lrow = lane >> 4;              // 0..3   (row within 4-row group)
    const int lcol = (lane & 15) * 4;        // 0..60  (col, 4 floats)
    // per-lane global source/dest for wide ops (4 rows x 64 h per instr)
    const float* gsrc0 = x   + seq_base + (size_t)lrow * H_DIM + h0 + lcol;
    float*       gdst0 = out + seq_base + (size_t)lrow * H_DIM + h0 + lcol;

    // Drain the scalar param loads so vmcnt bookkeeping below starts at 0.
    asm volatile("s_waitcnt vmcnt(0) lgkmcnt(0)" ::: "memory");

    // Issue 16 width-16 global->LDS loads for tile t into xbuf[buf].
    // LDS dest is wave-uniform base + lane*16 -> lands as [s_local][h_local].
    auto issue_tile = [&](int t, int buf) {
        const float* g = gsrc0 + (size_t)t * TS * H_DIM;
#pragma unroll
        for (int k = 0; k < 16; ++k) {
            __builtin_amdgcn_global_load_lds(
                (gbl_u32*)(g + (size_t)k * 4 * H_DIM),
                (lds_u32*)&xbuf[buf][k * 4][0],
                16, 0, 0);
        }
    };

    float mem = 0.0f;
    float ref = 0.0f;

    issue_tile(0, 0);
    issue_tile(1, 1);

    for (int t = 0; t < NT; ++t) {
        const int buf = t & 1;

        // Wait for tile t's 16 loads. Newer outstanding ops:
        //   t==0: L1(16)            -> vmcnt(16)
        //   t==1: L2+F0             -> vmcnt(32)
        //   t==NT-1: F(t-2)+F(t-1)  -> vmcnt(32)
        //   else: F(t-2)+L(t+1)+F(t-1) -> vmcnt(48)
        if (t == 0)                       asm volatile("s_waitcnt vmcnt(16)" ::: "memory");
        else if (t == 1 || t == NT - 1)   asm volatile("s_waitcnt vmcnt(32)" ::: "memory");
        else                              asm volatile("s_waitcnt vmcnt(48)" ::: "memory");
        __builtin_amdgcn_sched_barrier(0);

        // Compute 64 timesteps from xbuf[buf], spikes -> obuf[buf].
#pragma unroll
        for (int s = 0; s < TS; ++s) {
            const float xv   = xbuf[buf][s][lane];
            const float memn = __fadd_rn(__fmul_rn(decay, mem), xv);  // 2 roundings
            ref = fmaxf(__fadd_rn(ref, -1.0f), 0.0f);                 // clamp(ref-1,0)
            const bool spk_b = (ref == 0.0f) & (memn > thr);
            mem = spk_b ? 0.0f : memn;                                // exact reset
            ref = __fadd_rn(ref, spk_b ? 5.0f : 0.0f);                // exact
            obuf[buf][s][lane] = spk_b ? 1.0f : 0.0f;
        }

        __builtin_amdgcn_wave_barrier();

        // Prefetch tile t+2 into xbuf[buf] (same parity). All xbuf reads above
        // were consumed (lgkm-waited) before their use; drain DS queue before
        // the async LDS writes can land.
        if (t + 2 < NT) {
            asm volatile("s_waitcnt lgkmcnt(0)" ::: "memory");
            issue_tile(t + 2, buf);
        }

        __builtin_amdgcn_wave_barrier();

        // Flush obuf[buf] -> out tile t: 16x 1KB nontemporal dwordx4 stores.
        {
            float*       gd   = gdst0 + (size_t)t * TS * H_DIM;
            const float* lsrc = &obuf[buf][0][0];
#pragma unroll
            for (int k = 0; k < 16; ++k) {
                const f32x4 v = *(const f32x4*)(lsrc + k * 256 + lane * 4);
                __builtin_nontemporal_store(v, (f32x4*)(gd + (size_t)k * 4 * H_DIM));
            }
        }
    }
}

extern "C" void kernel_launch(void* const* d_in, const int* in_sizes, int n_in,
                              void* d_out, int out_size, void* d_ws, size_t ws_size,
                              hipStream_t stream) {
    const float* x     = (const float*)d_in[0];
    const float* thr   = (const float*)d_in[1];
    const float* decay = (const float*)d_in[2];
    float*       out   = (float*)d_out;

    // 512 blocks x 64 threads = 32768 sequences; 2 single-wave blocks per CU.
    lif_kernel<<<dim3(512), dim3(64), 0, stream>>>(x, thr, decay, out);
}